// Round 1
// baseline (4374.867 us; speedup 1.0000x reference)
//
#include <hip/hip_runtime.h>
#include <math.h>

// ---------------------------------------------------------------------------
// GEMM: Y[N,128] = relu(X[N,K] @ W[K,128] + bias), fp32, K in {256,128}
// Block: 256 threads, tile BM=64 x BN=128, BK=32. Each thread: 8x4 outputs.
// ---------------------------------------------------------------------------
template <int K>
__global__ __launch_bounds__(256, 2) void gemm_relu_kernel(
    const float* __restrict__ X, const float* __restrict__ W,
    const float* __restrict__ bias, float* __restrict__ Y, int N) {
  constexpr int BM = 64, BK = 32;
  __shared__ float As[BM][BK];    // 8 KB
  __shared__ float Bs[BK][128];   // 16 KB

  const int tid = threadIdx.x;
  const int m0 = blockIdx.x * BM;
  const int tx = tid & 31;   // col group: 32 groups x 4 cols
  const int ty = tid >> 5;   // row group: 8 groups x 8 rows

  float acc[8][4] = {};

  for (int k0 = 0; k0 < K; k0 += BK) {
    // Stage A tile: 64x32 floats = 512 float4, 2 per thread
    #pragma unroll
    for (int i = tid; i < 512; i += 256) {
      int r = i >> 3;
      int c = (i & 7) << 2;
      int gr = m0 + r;
      float4 v = make_float4(0.f, 0.f, 0.f, 0.f);
      if (gr < N) v = *reinterpret_cast<const float4*>(&X[(long long)gr * K + k0 + c]);
      *reinterpret_cast<float4*>(&As[r][c]) = v;
    }
    // Stage B tile: 32x128 floats = 1024 float4, 4 per thread
    #pragma unroll
    for (int i = tid; i < 1024; i += 256) {
      int r = i >> 5;
      int c = (i & 31) << 2;
      *reinterpret_cast<float4*>(&Bs[r][c]) =
          *reinterpret_cast<const float4*>(&W[(long long)(k0 + r) * 128 + c]);
    }
    __syncthreads();

    #pragma unroll
    for (int kk = 0; kk < BK; ++kk) {
      float a[8];
      #pragma unroll
      for (int r = 0; r < 8; ++r) a[r] = As[ty * 8 + r][kk];
      float4 bq = *reinterpret_cast<const float4*>(&Bs[kk][tx * 4]);
      float bb[4] = {bq.x, bq.y, bq.z, bq.w};
      #pragma unroll
      for (int r = 0; r < 8; ++r)
        #pragma unroll
        for (int c = 0; c < 4; ++c) acc[r][c] += a[r] * bb[c];
    }
    __syncthreads();
  }

  float4 bv = *reinterpret_cast<const float4*>(&bias[tx * 4]);
  float bb[4] = {bv.x, bv.y, bv.z, bv.w};
  #pragma unroll
  for (int r = 0; r < 8; ++r) {
    int gr = m0 + ty * 8 + r;
    if (gr < N) {
      float4 o;
      o.x = fmaxf(acc[r][0] + bb[0], 0.f);
      o.y = fmaxf(acc[r][1] + bb[1], 0.f);
      o.z = fmaxf(acc[r][2] + bb[2], 0.f);
      o.w = fmaxf(acc[r][3] + bb[3], 0.f);
      *reinterpret_cast<float4*>(&Y[(long long)gr * 128 + tx * 4]) = o;
    }
  }
}

// ---------------------------------------------------------------------------
// SpMM scatter: Y[dst[e], :] += w[e] * X[src[e], :], D = 128.
// 32 threads per edge, each thread: float4 gather + 4 scalar atomics.
// ---------------------------------------------------------------------------
__global__ __launch_bounds__(256) void spmm_atomic_kernel(
    const int* __restrict__ src, const int* __restrict__ dst,
    const float* __restrict__ w, const float* __restrict__ X,
    float* __restrict__ Y, int E) {
  int tid = blockIdx.x * 256 + threadIdx.x;
  int e = tid >> 5;
  int q = tid & 31;
  if (e >= E) return;
  int s = src[e];
  int d = dst[e];
  float ww = w[e];
  float4 v = *reinterpret_cast<const float4*>(&X[(long long)s * 128 + q * 4]);
  float* yp = &Y[(long long)d * 128 + q * 4];
  atomicAdd(yp + 0, ww * v.x);
  atomicAdd(yp + 1, ww * v.y);
  atomicAdd(yp + 2, ww * v.z);
  atomicAdd(yp + 3, ww * v.w);
}

// ---------------------------------------------------------------------------
// Normalize + concat into outputs.
// Block = 256 threads = 4 waves; block n handles doc node n.
//   wave 0: l2norm(r0[n])            -> out[n*384 + 0..127]
//   wave 1: l2norm([r1l[n],rwe[n]])  -> out[n*384 + 128..383]
//   wave 2: l2norm(r0s[n])           -> out[DOC + n*384 + 0..127]
//   wave 3: l2norm([r1sl[n],rwe[n]]) -> out[DOC + n*384 + 128..383]
// ---------------------------------------------------------------------------
__global__ __launch_bounds__(256) void normalize_kernel(
    const float* __restrict__ r0, const float* __restrict__ r1l,
    const float* __restrict__ r0s, const float* __restrict__ r1sl,
    const float* __restrict__ rwe, float* __restrict__ out, int N0) {
  int n = blockIdx.x;
  int wave = threadIdx.x >> 6;
  int lane = threadIdx.x & 63;
  const long long DOCOFF = (long long)N0 * 384;

  const float* a;
  const float* b = nullptr;
  float* o;
  switch (wave) {
    case 0: a = r0 + (long long)n * 128;   o = out + (long long)n * 384; break;
    case 1: a = r1l + (long long)n * 128;  b = rwe + (long long)n * 128;
            o = out + (long long)n * 384 + 128; break;
    case 2: a = r0s + (long long)n * 128;  o = out + DOCOFF + (long long)n * 384; break;
    default: a = r1sl + (long long)n * 128; b = rwe + (long long)n * 128;
            o = out + DOCOFF + (long long)n * 384 + 128; break;
  }

  float v0 = a[lane];
  float v1 = a[lane + 64];
  float v2 = 0.f, v3 = 0.f;
  if (b) { v2 = b[lane]; v3 = b[lane + 64]; }
  float s = v0 * v0 + v1 * v1 + v2 * v2 + v3 * v3;
  #pragma unroll
  for (int off = 32; off; off >>= 1) s += __shfl_xor(s, off);
  float inv = 1.0f / (sqrtf(s) + 1e-9f);
  o[lane] = v0 * inv;
  o[lane + 64] = v1 * inv;
  if (b) {
    o[lane + 128] = v2 * inv;
    o[lane + 192] = v3 * inv;
  }
}

// ---------------------------------------------------------------------------
extern "C" void kernel_launch(void* const* d_in, const int* in_sizes, int n_in,
                              void* d_out, int out_size, void* d_ws,
                              size_t ws_size, hipStream_t stream) {
  const float* x1  = (const float*)d_in[0];
  const float* x2  = (const float*)d_in[1];
  const float* wem = (const float*)d_in[2];
  const float* W1a = (const float*)d_in[3];
  const float* b1a = (const float*)d_in[4];
  const float* W1b = (const float*)d_in[5];
  const float* b1b = (const float*)d_in[6];
  const float* W2a = (const float*)d_in[7];
  const float* b2a = (const float*)d_in[8];
  const float* W2b = (const float*)d_in[9];
  const float* b2b = (const float*)d_in[10];
  const int*   e11s = (const int*)d_in[11];
  const int*   e11d = (const int*)d_in[12];
  const float* e11w = (const float*)d_in[13];
  const int*   e22s = (const int*)d_in[14];
  const int*   e22d = (const int*)d_in[15];
  const float* e22w = (const float*)d_in[16];
  const int*   e01s = (const int*)d_in[17];
  const int*   e01d = (const int*)d_in[18];
  const float* e01w = (const float*)d_in[19];
  const int*   e02s = (const int*)d_in[20];
  const int*   e02d = (const int*)d_in[21];
  const float* e02w = (const float*)d_in[22];

  const int N0 = 10000;
  const int N1 = in_sizes[0] / 256;   // 50000
  const int N2 = in_sizes[1] / 256;   // 30000
  const int E11 = in_sizes[11];
  const int E22 = in_sizes[14];
  const int E01 = in_sizes[17];
  const int E02 = in_sizes[20];

  float* out = (float*)d_out;

  // Workspace layout (all fp32, 128 cols each)
  float* p = (float*)d_ws;
  float* l1_1 = p; p += (long long)N1 * 128;
  float* l1_2 = p; p += (long long)N2 * 128;
  float* l2_1 = p; p += (long long)N1 * 128;
  float* l2_2 = p; p += (long long)N2 * 128;
  float* zstart = p;                       // atomic-accumulated region starts
  float* h11  = p; p += (long long)N1 * 128;
  float* h22  = p; p += (long long)N2 * 128;
  float* r0   = p; p += (long long)N0 * 128;
  float* r0s  = p; p += (long long)N0 * 128;
  float* r1l  = p; p += (long long)N0 * 128;
  float* r1sl = p; p += (long long)N0 * 128;
  float* r1we = p; p += (long long)N0 * 128;
  size_t zbytes = (size_t)((char*)p - (char*)zstart);

  hipMemsetAsync(zstart, 0, zbytes, stream);

  // Layer 1 (identity-adjacency GCN = dense GEMM + relu)
  gemm_relu_kernel<256><<<(N1 + 63) / 64, 256, 0, stream>>>(x1, W1a, b1a, l1_1, N1);
  gemm_relu_kernel<256><<<(N2 + 63) / 64, 256, 0, stream>>>(x2, W2a, b2a, l1_2, N2);

  // Layer 2: spmm then GEMM + relu
  spmm_atomic_kernel<<<(E11 * 32 + 255) / 256, 256, 0, stream>>>(e11s, e11d, e11w, l1_1, h11, E11);
  spmm_atomic_kernel<<<(E22 * 32 + 255) / 256, 256, 0, stream>>>(e22s, e22d, e22w, l1_2, h22, E22);
  gemm_relu_kernel<128><<<(N1 + 63) / 64, 256, 0, stream>>>(h11, W1b, b1b, l2_1, N1);
  gemm_relu_kernel<128><<<(N2 + 63) / 64, 256, 0, stream>>>(h22, W2b, b2b, l2_2, N2);

  // Aggregate to document nodes
  spmm_atomic_kernel<<<(E01 * 32 + 255) / 256, 256, 0, stream>>>(e01s, e01d, e01w, l2_1, r0, E01);
  spmm_atomic_kernel<<<(E01 * 32 + 255) / 256, 256, 0, stream>>>(e01s, e01d, e01w, l1_1, r0s, E01);
  spmm_atomic_kernel<<<(E02 * 32 + 255) / 256, 256, 0, stream>>>(e02s, e02d, e02w, l2_2, r1l, E02);
  spmm_atomic_kernel<<<(E02 * 32 + 255) / 256, 256, 0, stream>>>(e02s, e02d, e02w, l1_2, r1sl, E02);
  spmm_atomic_kernel<<<(E02 * 32 + 255) / 256, 256, 0, stream>>>(e02s, e02d, e02w, wem, r1we, E02);

  // Normalize + concat into (doc, doc_svd)
  normalize_kernel<<<N0, 256, 0, stream>>>(r0, r1l, r0s, r1sl, r1we, out, N0);
}

// Round 2
// 826.363 us; speedup vs baseline: 5.2941x; 5.2941x over previous
//
#include <hip/hip_runtime.h>
#include <math.h>

// ---------------------------------------------------------------------------
// GEMM: Y[N,128] = relu(X[N,K] @ W[K,128] + bias), fp32, K in {256,128}
// ---------------------------------------------------------------------------
template <int K>
__global__ __launch_bounds__(256, 2) void gemm_relu_kernel(
    const float* __restrict__ X, const float* __restrict__ W,
    const float* __restrict__ bias, float* __restrict__ Y, int N) {
  constexpr int BM = 64, BK = 32;
  __shared__ float As[BM][BK];
  __shared__ float Bs[BK][128];

  const int tid = threadIdx.x;
  const int m0 = blockIdx.x * BM;
  const int tx = tid & 31;
  const int ty = tid >> 5;

  float acc[8][4] = {};

  for (int k0 = 0; k0 < K; k0 += BK) {
    #pragma unroll
    for (int i = tid; i < 512; i += 256) {
      int r = i >> 3;
      int c = (i & 7) << 2;
      int gr = m0 + r;
      float4 v = make_float4(0.f, 0.f, 0.f, 0.f);
      if (gr < N) v = *reinterpret_cast<const float4*>(&X[(long long)gr * K + k0 + c]);
      *reinterpret_cast<float4*>(&As[r][c]) = v;
    }
    #pragma unroll
    for (int i = tid; i < 1024; i += 256) {
      int r = i >> 5;
      int c = (i & 31) << 2;
      *reinterpret_cast<float4*>(&Bs[r][c]) =
          *reinterpret_cast<const float4*>(&W[(long long)(k0 + r) * 128 + c]);
    }
    __syncthreads();

    #pragma unroll
    for (int kk = 0; kk < BK; ++kk) {
      float a[8];
      #pragma unroll
      for (int r = 0; r < 8; ++r) a[r] = As[ty * 8 + r][kk];
      float4 bq = *reinterpret_cast<const float4*>(&Bs[kk][tx * 4]);
      float bb[4] = {bq.x, bq.y, bq.z, bq.w};
      #pragma unroll
      for (int r = 0; r < 8; ++r)
        #pragma unroll
        for (int c = 0; c < 4; ++c) acc[r][c] += a[r] * bb[c];
    }
    __syncthreads();
  }

  float4 bv = *reinterpret_cast<const float4*>(&bias[tx * 4]);
  float bb[4] = {bv.x, bv.y, bv.z, bv.w};
  #pragma unroll
  for (int r = 0; r < 8; ++r) {
    int gr = m0 + ty * 8 + r;
    if (gr < N) {
      float4 o;
      o.x = fmaxf(acc[r][0] + bb[0], 0.f);
      o.y = fmaxf(acc[r][1] + bb[1], 0.f);
      o.z = fmaxf(acc[r][2] + bb[2], 0.f);
      o.w = fmaxf(acc[r][3] + bb[3], 0.f);
      *reinterpret_cast<float4*>(&Y[(long long)gr * 128 + tx * 4]) = o;
    }
  }
}

// ---------------------------------------------------------------------------
// CSR build: histogram -> scan -> scatter packed (src, w) records.
// ---------------------------------------------------------------------------
__global__ __launch_bounds__(256) void hist_kernel(
    const int* __restrict__ dst, int E, int* __restrict__ counts) {
  int e = blockIdx.x * 256 + threadIdx.x;
  if (e < E) atomicAdd(&counts[dst[e]], 1);
}

// One block per array; exclusive scan of counts[n] -> offs[n] and cursor copy.
__global__ __launch_bounds__(1024) void scan4_kernel(
    const int* __restrict__ c0, int* __restrict__ o0, int* __restrict__ k0, int n0,
    const int* __restrict__ c1, int* __restrict__ o1, int* __restrict__ k1, int n1,
    const int* __restrict__ c2, int* __restrict__ o2, int* __restrict__ k2, int n2,
    const int* __restrict__ c3, int* __restrict__ o3, int* __restrict__ k3, int n3) {
  const int* c; int* o; int* kc; int n;
  switch (blockIdx.x) {
    case 0: c = c0; o = o0; kc = k0; n = n0; break;
    case 1: c = c1; o = o1; kc = k1; n = n1; break;
    case 2: c = c2; o = o2; kc = k2; n = n2; break;
    default: c = c3; o = o3; kc = k3; n = n3; break;
  }
  __shared__ int sh[1024];
  const int tid = threadIdx.x;
  int carry = 0;
  for (int base = 0; base < n; base += 8192) {
    int i0 = base + tid * 8;
    int v[8], loc[8];
    int s = 0;
    #pragma unroll
    for (int k = 0; k < 8; ++k) {
      int i = i0 + k;
      v[k] = (i < n) ? c[i] : 0;
      loc[k] = s;
      s += v[k];
    }
    sh[tid] = s;
    __syncthreads();
    for (int off = 1; off < 1024; off <<= 1) {
      int t = (tid >= off) ? sh[tid - off] : 0;
      __syncthreads();
      sh[tid] += t;
      __syncthreads();
    }
    int excl = sh[tid] - s;
    int total = sh[1023];
    #pragma unroll
    for (int k = 0; k < 8; ++k) {
      int i = i0 + k;
      if (i < n) {
        int val = carry + excl + loc[k];
        o[i] = val;
        kc[i] = val;
      }
    }
    carry += total;
    __syncthreads();
  }
}

__global__ __launch_bounds__(256) void scatter_kernel(
    const int* __restrict__ src, const int* __restrict__ dst,
    const float* __restrict__ w, int E, int* __restrict__ cursor,
    int2* __restrict__ packed) {
  int e = blockIdx.x * 256 + threadIdx.x;
  if (e >= E) return;
  int p = atomicAdd(&cursor[dst[e]], 1);
  packed[p] = make_int2(src[e], __float_as_int(w[e]));
}

// ---------------------------------------------------------------------------
// Pull-mode SpMM: one wave per dst row, lane handles 2 consecutive floats.
// ---------------------------------------------------------------------------
__global__ __launch_bounds__(256) void pull_spmm_kernel(
    const int* __restrict__ offs, const int2* __restrict__ packed,
    const float* __restrict__ X, float* __restrict__ Y, int N) {
  int row = blockIdx.x * 4 + (threadIdx.x >> 6);
  int lane = threadIdx.x & 63;
  if (row >= N) return;
  int beg = offs[row], end = offs[row + 1];
  const float2* X2 = (const float2*)X;
  float2 acc = make_float2(0.f, 0.f);
  int j = beg;
  for (; j + 1 < end; j += 2) {
    int2 p0 = packed[j];
    int2 p1 = packed[j + 1];
    float2 v0 = X2[(long long)p0.x * 64 + lane];
    float2 v1 = X2[(long long)p1.x * 64 + lane];
    float w0 = __int_as_float(p0.y);
    float w1 = __int_as_float(p1.y);
    acc.x += w0 * v0.x + w1 * v1.x;
    acc.y += w0 * v0.y + w1 * v1.y;
  }
  if (j < end) {
    int2 p0 = packed[j];
    float2 v0 = X2[(long long)p0.x * 64 + lane];
    float w0 = __int_as_float(p0.y);
    acc.x += w0 * v0.x;
    acc.y += w0 * v0.y;
  }
  ((float2*)Y)[(long long)row * 64 + lane] = acc;
}

__device__ __forceinline__ float wave_sum64(float s) {
  #pragma unroll
  for (int off = 32; off; off >>= 1) s += __shfl_xor(s, off);
  return s;
}

// e01 aggregation: acc both l2_1 (-> doc r0) and l1_1 (-> doc_svd r0s),
// l2norm each, write out columns [0,128).
__global__ __launch_bounds__(256) void pull_doc2_kernel(
    const int* __restrict__ offs, const int2* __restrict__ packed,
    const float* __restrict__ Xa, const float* __restrict__ Xb,
    float* __restrict__ out, int N0) {
  int row = blockIdx.x * 4 + (threadIdx.x >> 6);
  int lane = threadIdx.x & 63;
  if (row >= N0) return;
  int beg = offs[row], end = offs[row + 1];
  const float2* A2 = (const float2*)Xa;
  const float2* B2 = (const float2*)Xb;
  float2 a = make_float2(0.f, 0.f), b = make_float2(0.f, 0.f);
  for (int j = beg; j < end; ++j) {
    int2 p = packed[j];
    float w = __int_as_float(p.y);
    float2 va = A2[(long long)p.x * 64 + lane];
    float2 vb = B2[(long long)p.x * 64 + lane];
    a.x += w * va.x; a.y += w * va.y;
    b.x += w * vb.x; b.y += w * vb.y;
  }
  const long long DOC = (long long)N0 * 384;
  float sa = wave_sum64(a.x * a.x + a.y * a.y);
  float inva = 1.0f / (sqrtf(sa) + 1e-9f);
  ((float2*)&out[(long long)row * 384])[lane] = make_float2(a.x * inva, a.y * inva);
  float sb = wave_sum64(b.x * b.x + b.y * b.y);
  float invb = 1.0f / (sqrtf(sb) + 1e-9f);
  ((float2*)&out[DOC + (long long)row * 384])[lane] = make_float2(b.x * invb, b.y * invb);
}

// e02 aggregation: acc l2_2, l1_2, wem; l2norm over 256-dim concats, write
// out columns [128,384) of both doc and doc_svd.
__global__ __launch_bounds__(256) void pull_doc3_kernel(
    const int* __restrict__ offs, const int2* __restrict__ packed,
    const float* __restrict__ Xa, const float* __restrict__ Xb,
    const float* __restrict__ Xw, float* __restrict__ out, int N0) {
  int row = blockIdx.x * 4 + (threadIdx.x >> 6);
  int lane = threadIdx.x & 63;
  if (row >= N0) return;
  int beg = offs[row], end = offs[row + 1];
  const float2* A2 = (const float2*)Xa;
  const float2* B2 = (const float2*)Xb;
  const float2* W2 = (const float2*)Xw;
  float2 a = make_float2(0.f, 0.f), b = make_float2(0.f, 0.f), wv = make_float2(0.f, 0.f);
  for (int j = beg; j < end; ++j) {
    int2 p = packed[j];
    float w = __int_as_float(p.y);
    float2 va = A2[(long long)p.x * 64 + lane];
    float2 vb = B2[(long long)p.x * 64 + lane];
    float2 vw = W2[(long long)p.x * 64 + lane];
    a.x += w * va.x; a.y += w * va.y;
    b.x += w * vb.x; b.y += w * vb.y;
    wv.x += w * vw.x; wv.y += w * vw.y;
  }
  const long long DOC = (long long)N0 * 384;
  float sw_part = wv.x * wv.x + wv.y * wv.y;
  float sa = wave_sum64(a.x * a.x + a.y * a.y + sw_part);
  float inva = 1.0f / (sqrtf(sa) + 1e-9f);
  float* o0 = &out[(long long)row * 384 + 128];
  ((float2*)o0)[lane] = make_float2(a.x * inva, a.y * inva);
  ((float2*)(o0 + 128))[lane] = make_float2(wv.x * inva, wv.y * inva);
  float sb = wave_sum64(b.x * b.x + b.y * b.y + sw_part);
  float invb = 1.0f / (sqrtf(sb) + 1e-9f);
  float* o1 = &out[DOC + (long long)row * 384 + 128];
  ((float2*)o1)[lane] = make_float2(b.x * invb, b.y * invb);
  ((float2*)(o1 + 128))[lane] = make_float2(wv.x * invb, wv.y * invb);
}

// ---------------------------------------------------------------------------
extern "C" void kernel_launch(void* const* d_in, const int* in_sizes, int n_in,
                              void* d_out, int out_size, void* d_ws,
                              size_t ws_size, hipStream_t stream) {
  const float* x1  = (const float*)d_in[0];
  const float* x2  = (const float*)d_in[1];
  const float* wem = (const float*)d_in[2];
  const float* W1a = (const float*)d_in[3];
  const float* b1a = (const float*)d_in[4];
  const float* W1b = (const float*)d_in[5];
  const float* b1b = (const float*)d_in[6];
  const float* W2a = (const float*)d_in[7];
  const float* b2a = (const float*)d_in[8];
  const float* W2b = (const float*)d_in[9];
  const float* b2b = (const float*)d_in[10];
  const int*   e11s = (const int*)d_in[11];
  const int*   e11d = (const int*)d_in[12];
  const float* e11w = (const float*)d_in[13];
  const int*   e22s = (const int*)d_in[14];
  const int*   e22d = (const int*)d_in[15];
  const float* e22w = (const float*)d_in[16];
  const int*   e01s = (const int*)d_in[17];
  const int*   e01d = (const int*)d_in[18];
  const float* e01w = (const float*)d_in[19];
  const int*   e02s = (const int*)d_in[20];
  const int*   e02d = (const int*)d_in[21];
  const float* e02w = (const float*)d_in[22];

  const int N0 = 10000;
  const int N1 = in_sizes[0] / 256;
  const int N2 = in_sizes[1] / 256;
  const int E11 = in_sizes[11];
  const int E22 = in_sizes[14];
  const int E01 = in_sizes[17];
  const int E02 = in_sizes[20];

  float* out = (float*)d_out;

  // ---- workspace layout ----
  char* base = (char*)d_ws;
  auto alloc = [&](size_t bytes) -> void* {
    void* r = (void*)base;
    base += (bytes + 255) & ~(size_t)255;
    return r;
  };
  float* l1_1 = (float*)alloc((size_t)N1 * 128 * 4);
  float* l1_2 = (float*)alloc((size_t)N2 * 128 * 4);
  float* l2_1 = (float*)alloc((size_t)N1 * 128 * 4);
  float* l2_2 = (float*)alloc((size_t)N2 * 128 * 4);
  float* h11  = (float*)alloc((size_t)N1 * 128 * 4);
  float* h22  = (float*)alloc((size_t)N2 * 128 * 4);

  const int P1 = (N1 + 1 + 63) & ~63;  // padded counts lengths
  const int P2 = (N2 + 1 + 63) & ~63;
  const int P0 = (N0 + 1 + 63) & ~63;
  int* cnt_all = (int*)alloc((size_t)(P1 + P2 + P0 + P0) * 4);
  int* cnt11 = cnt_all;
  int* cnt22 = cnt_all + P1;
  int* cnt01 = cnt_all + P1 + P2;
  int* cnt02 = cnt_all + P1 + P2 + P0;
  int* off11 = (int*)alloc((size_t)P1 * 4);
  int* off22 = (int*)alloc((size_t)P2 * 4);
  int* off01 = (int*)alloc((size_t)P0 * 4);
  int* off02 = (int*)alloc((size_t)P0 * 4);
  int* cur11 = (int*)alloc((size_t)P1 * 4);
  int* cur22 = (int*)alloc((size_t)P2 * 4);
  int* cur01 = (int*)alloc((size_t)P0 * 4);
  int* cur02 = (int*)alloc((size_t)P0 * 4);
  int2* pk11 = (int2*)alloc((size_t)E11 * 8);
  int2* pk22 = (int2*)alloc((size_t)E22 * 8);
  int2* pk01 = (int2*)alloc((size_t)E01 * 8);
  int2* pk02 = (int2*)alloc((size_t)E02 * 8);

  // ---- CSR build ----
  hipMemsetAsync(cnt_all, 0, (size_t)(P1 + P2 + P0 + P0) * 4, stream);
  hist_kernel<<<(E11 + 255) / 256, 256, 0, stream>>>(e11d, E11, cnt11);
  hist_kernel<<<(E22 + 255) / 256, 256, 0, stream>>>(e22d, E22, cnt22);
  hist_kernel<<<(E01 + 255) / 256, 256, 0, stream>>>(e01d, E01, cnt01);
  hist_kernel<<<(E02 + 255) / 256, 256, 0, stream>>>(e02d, E02, cnt02);
  scan4_kernel<<<4, 1024, 0, stream>>>(
      cnt11, off11, cur11, N1 + 1, cnt22, off22, cur22, N2 + 1,
      cnt01, off01, cur01, N0 + 1, cnt02, off02, cur02, N0 + 1);
  scatter_kernel<<<(E11 + 255) / 256, 256, 0, stream>>>(e11s, e11d, e11w, E11, cur11, pk11);
  scatter_kernel<<<(E22 + 255) / 256, 256, 0, stream>>>(e22s, e22d, e22w, E22, cur22, pk22);
  scatter_kernel<<<(E01 + 255) / 256, 256, 0, stream>>>(e01s, e01d, e01w, E01, cur01, pk01);
  scatter_kernel<<<(E02 + 255) / 256, 256, 0, stream>>>(e02s, e02d, e02w, E02, cur02, pk02);

  // ---- layer 1 GEMMs ----
  gemm_relu_kernel<256><<<(N1 + 63) / 64, 256, 0, stream>>>(x1, W1a, b1a, l1_1, N1);
  gemm_relu_kernel<256><<<(N2 + 63) / 64, 256, 0, stream>>>(x2, W2a, b2a, l1_2, N2);

  // ---- layer 2: pull-spmm then GEMM ----
  pull_spmm_kernel<<<(N1 + 3) / 4, 256, 0, stream>>>(off11, pk11, l1_1, h11, N1);
  pull_spmm_kernel<<<(N2 + 3) / 4, 256, 0, stream>>>(off22, pk22, l1_2, h22, N2);
  gemm_relu_kernel<128><<<(N1 + 63) / 64, 256, 0, stream>>>(h11, W1b, b1b, l2_1, N1);
  gemm_relu_kernel<128><<<(N2 + 63) / 64, 256, 0, stream>>>(h22, W2b, b2b, l2_2, N2);

  // ---- doc aggregation + l2norm + concat (fused) ----
  pull_doc2_kernel<<<(N0 + 3) / 4, 256, 0, stream>>>(off01, pk01, l2_1, l1_1, out, N0);
  pull_doc3_kernel<<<(N0 + 3) / 4, 256, 0, stream>>>(off02, pk02, l2_2, l1_2, wem, out, N0);
}

// Round 3
// 710.818 us; speedup vs baseline: 6.1547x; 1.1626x over previous
//
#include <hip/hip_runtime.h>
#include <math.h>

typedef __attribute__((ext_vector_type(8))) short short8;
typedef __attribute__((ext_vector_type(4))) float float4v;

__device__ __forceinline__ unsigned short f2bf(float f) {
  unsigned int u = __float_as_uint(f);
  unsigned int r = (u + 0x7fffu + ((u >> 16) & 1u)) >> 16;  // RNE
  return (unsigned short)r;
}

// ---------------------------------------------------------------------------
// Weight conversion: W[K][128] fp32 -> frag-major bf16 layout.
// Frag (nt, kb): lane L holds W[kb*32 + (L>>4)*8 + j][nt*16 + (L&15)], j=0..7,
// stored contiguously at ((nt*KB + kb)*64 + L)*8.
// One fused kernel converts all four weight matrices.
// ---------------------------------------------------------------------------
__global__ __launch_bounds__(256) void conv_w_kernel(
    const float* __restrict__ W1a, const float* __restrict__ W1b,
    const float* __restrict__ W2a, const float* __restrict__ W2b,
    unsigned short* __restrict__ F1a, unsigned short* __restrict__ F1b,
    unsigned short* __restrict__ F2a, unsigned short* __restrict__ F2b) {
  int t = blockIdx.x * 256 + threadIdx.x;
  const float* W; unsigned short* F; int KB;
  // segment sizes in threads: 8*KB*64
  if (t < 4096) { W = W1a; F = F1a; KB = 8; }
  else if (t < 6144) { W = W1b; F = F1b; KB = 4; t -= 4096; }
  else if (t < 10240) { W = W2a; F = F2a; KB = 8; t -= 6144; }
  else if (t < 12288) { W = W2b; F = F2b; KB = 4; t -= 10240; }
  else return;
  int lane = t & 63;
  int frag = t >> 6;
  int nt = frag / KB;
  int kb = frag - nt * KB;
  int k = kb * 32 + (lane >> 4) * 8;
  int n = nt * 16 + (lane & 15);
  unsigned short v[8];
  #pragma unroll
  for (int j = 0; j < 8; ++j) v[j] = f2bf(W[(long long)(k + j) * 128 + n]);
  unsigned short* o = F + ((long long)frag * 64 + lane) * 8;
  *reinterpret_cast<int4*>(o) = *reinterpret_cast<int4*>(v);
}

// ---------------------------------------------------------------------------
// MFMA GEMM: Y[N,128] = relu(X[N,K] @ W + bias). Block 256 = 4 waves, each
// wave does 16 rows x 128 cols (8 accumulator tiles). No LDS: A direct from
// global fp32 (converted in-register), B from frag-major bf16 (L2-hot).
// ---------------------------------------------------------------------------
template <int K>
__global__ __launch_bounds__(256) void gemm_mfma_kernel(
    const float* __restrict__ X, const unsigned short* __restrict__ Wf,
    const float* __restrict__ bias, float* __restrict__ Y, int N) {
  constexpr int KB = K / 32;
  const int lane = threadIdx.x & 63;
  const int wave = threadIdx.x >> 6;
  const int m_base = blockIdx.x * 64 + wave * 16;

  int arow = m_base + (lane & 15);
  if (arow >= N) arow = N - 1;
  const float* aptr = X + (long long)arow * K + (lane >> 4) * 8;

  float4v acc[8];
  #pragma unroll
  for (int nt = 0; nt < 8; ++nt) acc[nt] = (float4v)(0.f);

  #pragma unroll
  for (int kb = 0; kb < KB; ++kb) {
    float4 a0 = *reinterpret_cast<const float4*>(aptr + kb * 32);
    float4 a1 = *reinterpret_cast<const float4*>(aptr + kb * 32 + 4);
    unsigned short u[8];
    u[0] = f2bf(a0.x); u[1] = f2bf(a0.y); u[2] = f2bf(a0.z); u[3] = f2bf(a0.w);
    u[4] = f2bf(a1.x); u[5] = f2bf(a1.y); u[6] = f2bf(a1.z); u[7] = f2bf(a1.w);
    short8 afrag = *reinterpret_cast<short8*>(u);
    #pragma unroll
    for (int nt = 0; nt < 8; ++nt) {
      short8 bfrag = *reinterpret_cast<const short8*>(
          Wf + ((long long)(nt * KB + kb) * 64 + lane) * 8);
      acc[nt] = __builtin_amdgcn_mfma_f32_16x16x32_bf16(afrag, bfrag, acc[nt], 0, 0, 0);
    }
  }

  const int col = lane & 15;
  const int rbase = (lane >> 4) * 4;
  #pragma unroll
  for (int nt = 0; nt < 8; ++nt) {
    int n = nt * 16 + col;
    float b = bias[n];
    #pragma unroll
    for (int r = 0; r < 4; ++r) {
      int grow = m_base + rbase + r;
      if (grow < N) Y[(long long)grow * 128 + n] = fmaxf(acc[nt][r] + b, 0.f);
    }
  }
}

// ---------------------------------------------------------------------------
// CSR build: histogram -> scan -> scatter packed (src, w) records.
// ---------------------------------------------------------------------------
__global__ __launch_bounds__(256) void hist_kernel(
    const int* __restrict__ dst, int E, int* __restrict__ counts) {
  int e = blockIdx.x * 256 + threadIdx.x;
  if (e < E) atomicAdd(&counts[dst[e]], 1);
}

__global__ __launch_bounds__(1024) void scan4_kernel(
    const int* __restrict__ c0, int* __restrict__ o0, int* __restrict__ k0, int n0,
    const int* __restrict__ c1, int* __restrict__ o1, int* __restrict__ k1, int n1,
    const int* __restrict__ c2, int* __restrict__ o2, int* __restrict__ k2, int n2,
    const int* __restrict__ c3, int* __restrict__ o3, int* __restrict__ k3, int n3) {
  const int* c; int* o; int* kc; int n;
  switch (blockIdx.x) {
    case 0: c = c0; o = o0; kc = k0; n = n0; break;
    case 1: c = c1; o = o1; kc = k1; n = n1; break;
    case 2: c = c2; o = o2; kc = k2; n = n2; break;
    default: c = c3; o = o3; kc = k3; n = n3; break;
  }
  __shared__ int sh[1024];
  const int tid = threadIdx.x;
  int carry = 0;
  for (int base = 0; base < n; base += 8192) {
    int i0 = base + tid * 8;
    int v[8], loc[8];
    int s = 0;
    #pragma unroll
    for (int k = 0; k < 8; ++k) {
      int i = i0 + k;
      v[k] = (i < n) ? c[i] : 0;
      loc[k] = s;
      s += v[k];
    }
    sh[tid] = s;
    __syncthreads();
    for (int off = 1; off < 1024; off <<= 1) {
      int t = (tid >= off) ? sh[tid - off] : 0;
      __syncthreads();
      sh[tid] += t;
      __syncthreads();
    }
    int excl = sh[tid] - s;
    int total = sh[1023];
    #pragma unroll
    for (int k = 0; k < 8; ++k) {
      int i = i0 + k;
      if (i < n) {
        int val = carry + excl + loc[k];
        o[i] = val;
        kc[i] = val;
      }
    }
    carry += total;
    __syncthreads();
  }
}

__global__ __launch_bounds__(256) void scatter_kernel(
    const int* __restrict__ src, const int* __restrict__ dst,
    const float* __restrict__ w, int E, int* __restrict__ cursor,
    int2* __restrict__ packed) {
  int e = blockIdx.x * 256 + threadIdx.x;
  if (e >= E) return;
  int p = atomicAdd(&cursor[dst[e]], 1);
  packed[p] = make_int2(src[e], __float_as_int(w[e]));
}

// ---------------------------------------------------------------------------
// Pull-mode SpMM: one wave per dst row, lane handles 2 consecutive floats.
// ---------------------------------------------------------------------------
__global__ __launch_bounds__(256) void pull_spmm_kernel(
    const int* __restrict__ offs, const int2* __restrict__ packed,
    const float* __restrict__ X, float* __restrict__ Y, int N) {
  int row = blockIdx.x * 4 + (threadIdx.x >> 6);
  int lane = threadIdx.x & 63;
  if (row >= N) return;
  int beg = offs[row], end = offs[row + 1];
  const float2* X2 = (const float2*)X;
  float2 acc = make_float2(0.f, 0.f);
  int j = beg;
  for (; j + 1 < end; j += 2) {
    int2 p0 = packed[j];
    int2 p1 = packed[j + 1];
    float2 v0 = X2[(long long)p0.x * 64 + lane];
    float2 v1 = X2[(long long)p1.x * 64 + lane];
    float w0 = __int_as_float(p0.y);
    float w1 = __int_as_float(p1.y);
    acc.x += w0 * v0.x + w1 * v1.x;
    acc.y += w0 * v0.y + w1 * v1.y;
  }
  if (j < end) {
    int2 p0 = packed[j];
    float2 v0 = X2[(long long)p0.x * 64 + lane];
    float w0 = __int_as_float(p0.y);
    acc.x += w0 * v0.x;
    acc.y += w0 * v0.y;
  }
  ((float2*)Y)[(long long)row * 64 + lane] = acc;
}

__device__ __forceinline__ float wave_sum64(float s) {
  #pragma unroll
  for (int off = 32; off; off >>= 1) s += __shfl_xor(s, off);
  return s;
}

__global__ __launch_bounds__(256) void pull_doc2_kernel(
    const int* __restrict__ offs, const int2* __restrict__ packed,
    const float* __restrict__ Xa, const float* __restrict__ Xb,
    float* __restrict__ out, int N0) {
  int row = blockIdx.x * 4 + (threadIdx.x >> 6);
  int lane = threadIdx.x & 63;
  if (row >= N0) return;
  int beg = offs[row], end = offs[row + 1];
  const float2* A2 = (const float2*)Xa;
  const float2* B2 = (const float2*)Xb;
  float2 a = make_float2(0.f, 0.f), b = make_float2(0.f, 0.f);
  for (int j = beg; j < end; ++j) {
    int2 p = packed[j];
    float w = __int_as_float(p.y);
    float2 va = A2[(long long)p.x * 64 + lane];
    float2 vb = B2[(long long)p.x * 64 + lane];
    a.x += w * va.x; a.y += w * va.y;
    b.x += w * vb.x; b.y += w * vb.y;
  }
  const long long DOC = (long long)N0 * 384;
  float sa = wave_sum64(a.x * a.x + a.y * a.y);
  float inva = 1.0f / (sqrtf(sa) + 1e-9f);
  ((float2*)&out[(long long)row * 384])[lane] = make_float2(a.x * inva, a.y * inva);
  float sb = wave_sum64(b.x * b.x + b.y * b.y);
  float invb = 1.0f / (sqrtf(sb) + 1e-9f);
  ((float2*)&out[DOC + (long long)row * 384])[lane] = make_float2(b.x * invb, b.y * invb);
}

__global__ __launch_bounds__(256) void pull_doc3_kernel(
    const int* __restrict__ offs, const int2* __restrict__ packed,
    const float* __restrict__ Xa, const float* __restrict__ Xb,
    const float* __restrict__ Xw, float* __restrict__ out, int N0) {
  int row = blockIdx.x * 4 + (threadIdx.x >> 6);
  int lane = threadIdx.x & 63;
  if (row >= N0) return;
  int beg = offs[row], end = offs[row + 1];
  const float2* A2 = (const float2*)Xa;
  const float2* B2 = (const float2*)Xb;
  const float2* W2 = (const float2*)Xw;
  float2 a = make_float2(0.f, 0.f), b = make_float2(0.f, 0.f), wv = make_float2(0.f, 0.f);
  for (int j = beg; j < end; ++j) {
    int2 p = packed[j];
    float w = __int_as_float(p.y);
    float2 va = A2[(long long)p.x * 64 + lane];
    float2 vb = B2[(long long)p.x * 64 + lane];
    float2 vw = W2[(long long)p.x * 64 + lane];
    a.x += w * va.x; a.y += w * va.y;
    b.x += w * vb.x; b.y += w * vb.y;
    wv.x += w * vw.x; wv.y += w * vw.y;
  }
  const long long DOC = (long long)N0 * 384;
  float sw_part = wv.x * wv.x + wv.y * wv.y;
  float sa = wave_sum64(a.x * a.x + a.y * a.y + sw_part);
  float inva = 1.0f / (sqrtf(sa) + 1e-9f);
  float* o0 = &out[(long long)row * 384 + 128];
  ((float2*)o0)[lane] = make_float2(a.x * inva, a.y * inva);
  ((float2*)(o0 + 128))[lane] = make_float2(wv.x * inva, wv.y * inva);
  float sb = wave_sum64(b.x * b.x + b.y * b.y + sw_part);
  float invb = 1.0f / (sqrtf(sb) + 1e-9f);
  float* o1 = &out[DOC + (long long)row * 384 + 128];
  ((float2*)o1)[lane] = make_float2(b.x * invb, b.y * invb);
  ((float2*)(o1 + 128))[lane] = make_float2(wv.x * invb, wv.y * invb);
}

// ---------------------------------------------------------------------------
extern "C" void kernel_launch(void* const* d_in, const int* in_sizes, int n_in,
                              void* d_out, int out_size, void* d_ws,
                              size_t ws_size, hipStream_t stream) {
  const float* x1  = (const float*)d_in[0];
  const float* x2  = (const float*)d_in[1];
  const float* wem = (const float*)d_in[2];
  const float* W1a = (const float*)d_in[3];
  const float* b1a = (const float*)d_in[4];
  const float* W1b = (const float*)d_in[5];
  const float* b1b = (const float*)d_in[6];
  const float* W2a = (const float*)d_in[7];
  const float* b2a = (const float*)d_in[8];
  const float* W2b = (const float*)d_in[9];
  const float* b2b = (const float*)d_in[10];
  const int*   e11s = (const int*)d_in[11];
  const int*   e11d = (const int*)d_in[12];
  const float* e11w = (const float*)d_in[13];
  const int*   e22s = (const int*)d_in[14];
  const int*   e22d = (const int*)d_in[15];
  const float* e22w = (const float*)d_in[16];
  const int*   e01s = (const int*)d_in[17];
  const int*   e01d = (const int*)d_in[18];
  const float* e01w = (const float*)d_in[19];
  const int*   e02s = (const int*)d_in[20];
  const int*   e02d = (const int*)d_in[21];
  const float* e02w = (const float*)d_in[22];

  const int N0 = 10000;
  const int N1 = in_sizes[0] / 256;
  const int N2 = in_sizes[1] / 256;
  const int E11 = in_sizes[11];
  const int E22 = in_sizes[14];
  const int E01 = in_sizes[17];
  const int E02 = in_sizes[20];

  float* out = (float*)d_out;

  // ---- workspace layout ----
  char* base = (char*)d_ws;
  auto alloc = [&](size_t bytes) -> void* {
    void* r = (void*)base;
    base += (bytes + 255) & ~(size_t)255;
    return r;
  };
  float* l1_1 = (float*)alloc((size_t)N1 * 128 * 4);
  float* l1_2 = (float*)alloc((size_t)N2 * 128 * 4);
  float* l2_1 = (float*)alloc((size_t)N1 * 128 * 4);
  float* l2_2 = (float*)alloc((size_t)N2 * 128 * 4);
  float* h11  = (float*)alloc((size_t)N1 * 128 * 4);
  float* h22  = (float*)alloc((size_t)N2 * 128 * 4);

  // frag-major bf16 weights
  unsigned short* F1a = (unsigned short*)alloc(8 * 8 * 64 * 8 * 2);
  unsigned short* F1b = (unsigned short*)alloc(8 * 4 * 64 * 8 * 2);
  unsigned short* F2a = (unsigned short*)alloc(8 * 8 * 64 * 8 * 2);
  unsigned short* F2b = (unsigned short*)alloc(8 * 4 * 64 * 8 * 2);

  const int P1 = (N1 + 1 + 63) & ~63;
  const int P2 = (N2 + 1 + 63) & ~63;
  const int P0 = (N0 + 1 + 63) & ~63;
  int* cnt_all = (int*)alloc((size_t)(P1 + P2 + P0 + P0) * 4);
  int* cnt11 = cnt_all;
  int* cnt22 = cnt_all + P1;
  int* cnt01 = cnt_all + P1 + P2;
  int* cnt02 = cnt_all + P1 + P2 + P0;
  int* off11 = (int*)alloc((size_t)P1 * 4);
  int* off22 = (int*)alloc((size_t)P2 * 4);
  int* off01 = (int*)alloc((size_t)P0 * 4);
  int* off02 = (int*)alloc((size_t)P0 * 4);
  int* cur11 = (int*)alloc((size_t)P1 * 4);
  int* cur22 = (int*)alloc((size_t)P2 * 4);
  int* cur01 = (int*)alloc((size_t)P0 * 4);
  int* cur02 = (int*)alloc((size_t)P0 * 4);
  int2* pk11 = (int2*)alloc((size_t)E11 * 8);
  int2* pk22 = (int2*)alloc((size_t)E22 * 8);
  int2* pk01 = (int2*)alloc((size_t)E01 * 8);
  int2* pk02 = (int2*)alloc((size_t)E02 * 8);

  // ---- CSR build ----
  hipMemsetAsync(cnt_all, 0, (size_t)(P1 + P2 + P0 + P0) * 4, stream);
  hist_kernel<<<(E11 + 255) / 256, 256, 0, stream>>>(e11d, E11, cnt11);
  hist_kernel<<<(E22 + 255) / 256, 256, 0, stream>>>(e22d, E22, cnt22);
  hist_kernel<<<(E01 + 255) / 256, 256, 0, stream>>>(e01d, E01, cnt01);
  hist_kernel<<<(E02 + 255) / 256, 256, 0, stream>>>(e02d, E02, cnt02);
  scan4_kernel<<<4, 1024, 0, stream>>>(
      cnt11, off11, cur11, N1 + 1, cnt22, off22, cur22, N2 + 1,
      cnt01, off01, cur01, N0 + 1, cnt02, off02, cur02, N0 + 1);
  scatter_kernel<<<(E11 + 255) / 256, 256, 0, stream>>>(e11s, e11d, e11w, E11, cur11, pk11);
  scatter_kernel<<<(E22 + 255) / 256, 256, 0, stream>>>(e22s, e22d, e22w, E22, cur22, pk22);
  scatter_kernel<<<(E01 + 255) / 256, 256, 0, stream>>>(e01s, e01d, e01w, E01, cur01, pk01);
  scatter_kernel<<<(E02 + 255) / 256, 256, 0, stream>>>(e02s, e02d, e02w, E02, cur02, pk02);

  // ---- weight conversion + layer 1 GEMMs (bf16 MFMA) ----
  conv_w_kernel<<<48, 256, 0, stream>>>(W1a, W1b, W2a, W2b, F1a, F1b, F2a, F2b);
  gemm_mfma_kernel<256><<<(N1 + 63) / 64, 256, 0, stream>>>(x1, F1a, b1a, l1_1, N1);
  gemm_mfma_kernel<256><<<(N2 + 63) / 64, 256, 0, stream>>>(x2, F2a, b2a, l1_2, N2);

  // ---- layer 2: pull-spmm then GEMM ----
  pull_spmm_kernel<<<(N1 + 3) / 4, 256, 0, stream>>>(off11, pk11, l1_1, h11, N1);
  pull_spmm_kernel<<<(N2 + 3) / 4, 256, 0, stream>>>(off22, pk22, l1_2, h22, N2);
  gemm_mfma_kernel<128><<<(N1 + 63) / 64, 256, 0, stream>>>(h11, F1b, b1b, l2_1, N1);
  gemm_mfma_kernel<128><<<(N2 + 63) / 64, 256, 0, stream>>>(h22, F2b, b2b, l2_2, N2);

  // ---- doc aggregation + l2norm + concat (fused) ----
  pull_doc2_kernel<<<(N0 + 3) / 4, 256, 0, stream>>>(off01, pk01, l2_1, l1_1, out, N0);
  pull_doc3_kernel<<<(N0 + 3) / 4, 256, 0, stream>>>(off02, pk02, l2_2, l1_2, wem, out, N0);
}

// Round 4
// 638.676 us; speedup vs baseline: 6.8499x; 1.1130x over previous
//
#include <hip/hip_runtime.h>
#include <math.h>

typedef __attribute__((ext_vector_type(8))) short short8;
typedef __attribute__((ext_vector_type(4))) float float4v;

#define CHUNK 4096

__device__ __forceinline__ unsigned short f2bf(float f) {
  unsigned int u = __float_as_uint(f);
  unsigned int r = (u + 0x7fffu + ((u >> 16) & 1u)) >> 16;  // RNE
  return (unsigned short)r;
}

// ---------------------------------------------------------------------------
// Weight conversion: W[K][128] fp32 -> frag-major bf16 layout.
// ---------------------------------------------------------------------------
__global__ __launch_bounds__(256) void conv_w_kernel(
    const float* __restrict__ W1a, const float* __restrict__ W1b,
    const float* __restrict__ W2a, const float* __restrict__ W2b,
    unsigned short* __restrict__ F1a, unsigned short* __restrict__ F1b,
    unsigned short* __restrict__ F2a, unsigned short* __restrict__ F2b) {
  int t = blockIdx.x * 256 + threadIdx.x;
  const float* W; unsigned short* F; int KB;
  if (t < 4096) { W = W1a; F = F1a; KB = 8; }
  else if (t < 6144) { W = W1b; F = F1b; KB = 4; t -= 4096; }
  else if (t < 10240) { W = W2a; F = F2a; KB = 8; t -= 6144; }
  else if (t < 12288) { W = W2b; F = F2b; KB = 4; t -= 10240; }
  else return;
  int lane = t & 63;
  int frag = t >> 6;
  int nt = frag / KB;
  int kb = frag - nt * KB;
  int k = kb * 32 + (lane >> 4) * 8;
  int n = nt * 16 + (lane & 15);
  unsigned short v[8];
  #pragma unroll
  for (int j = 0; j < 8; ++j) v[j] = f2bf(W[(long long)(k + j) * 128 + n]);
  unsigned short* o = F + ((long long)frag * 64 + lane) * 8;
  *reinterpret_cast<int4*>(o) = *reinterpret_cast<int4*>(v);
}

// ---------------------------------------------------------------------------
// MFMA GEMM: Y[N,128] = relu(X[N,K] @ W + bias). 4 waves/block, 16 rows/wave.
// ---------------------------------------------------------------------------
template <int K>
__global__ __launch_bounds__(256) void gemm_mfma_kernel(
    const float* __restrict__ X, const unsigned short* __restrict__ Wf,
    const float* __restrict__ bias, float* __restrict__ Y, int N) {
  constexpr int KB = K / 32;
  const int lane = threadIdx.x & 63;
  const int wave = threadIdx.x >> 6;
  const int m_base = blockIdx.x * 64 + wave * 16;

  int arow = m_base + (lane & 15);
  if (arow >= N) arow = N - 1;
  const float* aptr = X + (long long)arow * K + (lane >> 4) * 8;

  float4v acc[8];
  #pragma unroll
  for (int nt = 0; nt < 8; ++nt) acc[nt] = (float4v)(0.f);

  #pragma unroll
  for (int kb = 0; kb < KB; ++kb) {
    float4 a0 = *reinterpret_cast<const float4*>(aptr + kb * 32);
    float4 a1 = *reinterpret_cast<const float4*>(aptr + kb * 32 + 4);
    unsigned short u[8];
    u[0] = f2bf(a0.x); u[1] = f2bf(a0.y); u[2] = f2bf(a0.z); u[3] = f2bf(a0.w);
    u[4] = f2bf(a1.x); u[5] = f2bf(a1.y); u[6] = f2bf(a1.z); u[7] = f2bf(a1.w);
    short8 afrag = *reinterpret_cast<short8*>(u);
    #pragma unroll
    for (int nt = 0; nt < 8; ++nt) {
      short8 bfrag = *reinterpret_cast<const short8*>(
          Wf + ((long long)(nt * KB + kb) * 64 + lane) * 8);
      acc[nt] = __builtin_amdgcn_mfma_f32_16x16x32_bf16(afrag, bfrag, acc[nt], 0, 0, 0);
    }
  }

  const int col = lane & 15;
  const int rbase = (lane >> 4) * 4;
  #pragma unroll
  for (int nt = 0; nt < 8; ++nt) {
    int n = nt * 16 + col;
    float b = bias[n];
    #pragma unroll
    for (int r = 0; r < 4; ++r) {
      int grow = m_base + rbase + r;
      if (grow < N) Y[(long long)grow * 128 + n] = fmaxf(acc[nt][r] + b, 0.f);
    }
  }
}

// ---------------------------------------------------------------------------
// CSR build: fused histogram, 3-phase parallel scan, fused scatter.
// ---------------------------------------------------------------------------
__global__ __launch_bounds__(256) void hist_all_kernel(
    const int* __restrict__ d11, int E11, int* __restrict__ c11,
    const int* __restrict__ d22, int E22, int* __restrict__ c22,
    const int* __restrict__ d01, int E01, int* __restrict__ c01,
    const int* __restrict__ d02, int E02, int* __restrict__ c02) {
  int t = blockIdx.x * 256 + threadIdx.x;
  if (t < E11) { atomicAdd(&c11[d11[t]], 1); return; }
  t -= E11;
  if (t < E22) { atomicAdd(&c22[d22[t]], 1); return; }
  t -= E22;
  if (t < E01) { atomicAdd(&c01[d01[t]], 1); return; }
  t -= E01;
  if (t < E02) { atomicAdd(&c02[d02[t]], 1); }
}

// Phase A: per-chunk local exclusive scan + chunk totals.
__global__ __launch_bounds__(256) void scan_local_kernel(
    const int* __restrict__ c11, int* __restrict__ o11, int n11,
    const int* __restrict__ c22, int* __restrict__ o22, int n22,
    const int* __restrict__ c01, int* __restrict__ o01, int n01,
    const int* __restrict__ c02, int* __restrict__ o02, int n02,
    int nc11, int nc22, int nc01, int* __restrict__ chunkSums) {
  int b = blockIdx.x;
  const int* c; int* o; int n; int chunk;
  if (b < nc11) { c = c11; o = o11; n = n11; chunk = b; }
  else if (b < nc11 + nc22) { c = c22; o = o22; n = n22; chunk = b - nc11; }
  else if (b < nc11 + nc22 + nc01) { c = c01; o = o01; n = n01; chunk = b - nc11 - nc22; }
  else { c = c02; o = o02; n = n02; chunk = b - nc11 - nc22 - nc01; }
  int tid = threadIdx.x;
  int i0 = chunk * CHUNK + tid * 16;
  int loc[16];
  int s = 0;
  #pragma unroll
  for (int k = 0; k < 16; ++k) {
    int i = i0 + k;
    int x = (i < n) ? c[i] : 0;
    loc[k] = s;
    s += x;
  }
  __shared__ int sh[256];
  sh[tid] = s;
  __syncthreads();
  #pragma unroll
  for (int off = 1; off < 256; off <<= 1) {
    int t = (tid >= off) ? sh[tid - off] : 0;
    __syncthreads();
    sh[tid] += t;
    __syncthreads();
  }
  int excl = sh[tid] - s;
  #pragma unroll
  for (int k = 0; k < 16; ++k) {
    int i = i0 + k;
    if (i < n) o[i] = excl + loc[k];
  }
  if (tid == 255) chunkSums[b] = sh[255];
}

// Phase B: scan chunk totals (1 block), carry resets at array boundaries.
__global__ __launch_bounds__(64) void scan_sums_kernel(
    const int* __restrict__ chunkSums, int* __restrict__ chunkOffs,
    int nc11, int nc22, int nc01, int tc) {
  __shared__ int sh[64];
  int tid = threadIdx.x;
  if (tid < tc) sh[tid] = chunkSums[tid];
  __syncthreads();
  if (tid == 0) {
    int carry = 0;
    for (int b = 0; b < tc; ++b) {
      if (b == 0 || b == nc11 || b == nc11 + nc22 || b == nc11 + nc22 + nc01)
        carry = 0;
      chunkOffs[b] = carry;
      carry += sh[b];
    }
  }
}

// Phase C: add chunk offsets; write offs and cursor copies.
__global__ __launch_bounds__(256) void scan_add_kernel(
    int* __restrict__ o11, int* __restrict__ k11, int n11,
    int* __restrict__ o22, int* __restrict__ k22, int n22,
    int* __restrict__ o01, int* __restrict__ k01, int n01,
    int* __restrict__ o02, int* __restrict__ k02, int n02,
    int nc11, int nc22, int nc01, const int* __restrict__ chunkOffs) {
  int b = blockIdx.x;
  int* o; int* kc; int n; int chunk;
  if (b < nc11) { o = o11; kc = k11; n = n11; chunk = b; }
  else if (b < nc11 + nc22) { o = o22; kc = k22; n = n22; chunk = b - nc11; }
  else if (b < nc11 + nc22 + nc01) { o = o01; kc = k01; n = n01; chunk = b - nc11 - nc22; }
  else { o = o02; kc = k02; n = n02; chunk = b - nc11 - nc22 - nc01; }
  int add = chunkOffs[b];
  int tid = threadIdx.x;
  int i0 = chunk * CHUNK + tid * 16;
  #pragma unroll
  for (int k = 0; k < 16; ++k) {
    int i = i0 + k;
    if (i < n) {
      int val = o[i] + add;
      o[i] = val;
      kc[i] = val;
    }
  }
}

__global__ __launch_bounds__(256) void scatter_all_kernel(
    const int* __restrict__ s11, const int* __restrict__ d11,
    const float* __restrict__ w11, int E11, int* __restrict__ k11,
    int2* __restrict__ p11,
    const int* __restrict__ s22, const int* __restrict__ d22,
    const float* __restrict__ w22, int E22, int* __restrict__ k22,
    int2* __restrict__ p22,
    const int* __restrict__ s01, const int* __restrict__ d01,
    const float* __restrict__ w01, int E01, int* __restrict__ k01,
    int2* __restrict__ p01,
    const int* __restrict__ s02, const int* __restrict__ d02,
    const float* __restrict__ w02, int E02, int* __restrict__ k02,
    int2* __restrict__ p02) {
  int t = blockIdx.x * 256 + threadIdx.x;
  const int* src; const int* dst; const float* w; int* cur; int2* pk;
  if (t < E11) { src = s11; dst = d11; w = w11; cur = k11; pk = p11; }
  else { t -= E11;
    if (t < E22) { src = s22; dst = d22; w = w22; cur = k22; pk = p22; }
    else { t -= E22;
      if (t < E01) { src = s01; dst = d01; w = w01; cur = k01; pk = p01; }
      else { t -= E01;
        if (t < E02) { src = s02; dst = d02; w = w02; cur = k02; pk = p02; }
        else return;
      }
    }
  }
  int p = atomicAdd(&cur[dst[t]], 1);
  pk[p] = make_int2(src[t], __float_as_int(w[t]));
}

// ---------------------------------------------------------------------------
// Pull-mode SpMM: one wave per dst row, lane handles 2 consecutive floats.
// ---------------------------------------------------------------------------
__global__ __launch_bounds__(256) void pull_spmm_kernel(
    const int* __restrict__ offs, const int2* __restrict__ packed,
    const float* __restrict__ X, float* __restrict__ Y, int N) {
  int row = blockIdx.x * 4 + (threadIdx.x >> 6);
  int lane = threadIdx.x & 63;
  if (row >= N) return;
  int beg = offs[row], end = offs[row + 1];
  const float2* X2 = (const float2*)X;
  float2 acc = make_float2(0.f, 0.f);
  int j = beg;
  for (; j + 1 < end; j += 2) {
    int2 p0 = packed[j];
    int2 p1 = packed[j + 1];
    float2 v0 = X2[(long long)p0.x * 64 + lane];
    float2 v1 = X2[(long long)p1.x * 64 + lane];
    float w0 = __int_as_float(p0.y);
    float w1 = __int_as_float(p1.y);
    acc.x += w0 * v0.x + w1 * v1.x;
    acc.y += w0 * v0.y + w1 * v1.y;
  }
  if (j < end) {
    int2 p0 = packed[j];
    float2 v0 = X2[(long long)p0.x * 64 + lane];
    float w0 = __int_as_float(p0.y);
    acc.x += w0 * v0.x;
    acc.y += w0 * v0.y;
  }
  ((float2*)Y)[(long long)row * 64 + lane] = acc;
}

__device__ __forceinline__ float wave_sum64(float s) {
  #pragma unroll
  for (int off = 32; off; off >>= 1) s += __shfl_xor(s, off);
  return s;
}

__global__ __launch_bounds__(256) void pull_doc2_kernel(
    const int* __restrict__ offs, const int2* __restrict__ packed,
    const float* __restrict__ Xa, const float* __restrict__ Xb,
    float* __restrict__ out, int N0) {
  int row = blockIdx.x * 4 + (threadIdx.x >> 6);
  int lane = threadIdx.x & 63;
  if (row >= N0) return;
  int beg = offs[row], end = offs[row + 1];
  const float2* A2 = (const float2*)Xa;
  const float2* B2 = (const float2*)Xb;
  float2 a = make_float2(0.f, 0.f), b = make_float2(0.f, 0.f);
  for (int j = beg; j < end; ++j) {
    int2 p = packed[j];
    float w = __int_as_float(p.y);
    float2 va = A2[(long long)p.x * 64 + lane];
    float2 vb = B2[(long long)p.x * 64 + lane];
    a.x += w * va.x; a.y += w * va.y;
    b.x += w * vb.x; b.y += w * vb.y;
  }
  const long long DOC = (long long)N0 * 384;
  float sa = wave_sum64(a.x * a.x + a.y * a.y);
  float inva = 1.0f / (sqrtf(sa) + 1e-9f);
  ((float2*)&out[(long long)row * 384])[lane] = make_float2(a.x * inva, a.y * inva);
  float sb = wave_sum64(b.x * b.x + b.y * b.y);
  float invb = 1.0f / (sqrtf(sb) + 1e-9f);
  ((float2*)&out[DOC + (long long)row * 384])[lane] = make_float2(b.x * invb, b.y * invb);
}

__global__ __launch_bounds__(256) void pull_doc3_kernel(
    const int* __restrict__ offs, const int2* __restrict__ packed,
    const float* __restrict__ Xa, const float* __restrict__ Xb,
    const float* __restrict__ Xw, float* __restrict__ out, int N0) {
  int row = blockIdx.x * 4 + (threadIdx.x >> 6);
  int lane = threadIdx.x & 63;
  if (row >= N0) return;
  int beg = offs[row], end = offs[row + 1];
  const float2* A2 = (const float2*)Xa;
  const float2* B2 = (const float2*)Xb;
  const float2* W2 = (const float2*)Xw;
  float2 a = make_float2(0.f, 0.f), b = make_float2(0.f, 0.f), wv = make_float2(0.f, 0.f);
  for (int j = beg; j < end; ++j) {
    int2 p = packed[j];
    float w = __int_as_float(p.y);
    float2 va = A2[(long long)p.x * 64 + lane];
    float2 vb = B2[(long long)p.x * 64 + lane];
    float2 vw = W2[(long long)p.x * 64 + lane];
    a.x += w * va.x; a.y += w * va.y;
    b.x += w * vb.x; b.y += w * vb.y;
    wv.x += w * vw.x; wv.y += w * vw.y;
  }
  const long long DOC = (long long)N0 * 384;
  float sw_part = wv.x * wv.x + wv.y * wv.y;
  float sa = wave_sum64(a.x * a.x + a.y * a.y + sw_part);
  float inva = 1.0f / (sqrtf(sa) + 1e-9f);
  float* o0 = &out[(long long)row * 384 + 128];
  ((float2*)o0)[lane] = make_float2(a.x * inva, a.y * inva);
  ((float2*)(o0 + 128))[lane] = make_float2(wv.x * inva, wv.y * inva);
  float sb = wave_sum64(b.x * b.x + b.y * b.y + sw_part);
  float invb = 1.0f / (sqrtf(sb) + 1e-9f);
  float* o1 = &out[DOC + (long long)row * 384 + 128];
  ((float2*)o1)[lane] = make_float2(b.x * invb, b.y * invb);
  ((float2*)(o1 + 128))[lane] = make_float2(wv.x * invb, wv.y * invb);
}

// ---------------------------------------------------------------------------
extern "C" void kernel_launch(void* const* d_in, const int* in_sizes, int n_in,
                              void* d_out, int out_size, void* d_ws,
                              size_t ws_size, hipStream_t stream) {
  const float* x1  = (const float*)d_in[0];
  const float* x2  = (const float*)d_in[1];
  const float* wem = (const float*)d_in[2];
  const float* W1a = (const float*)d_in[3];
  const float* b1a = (const float*)d_in[4];
  const float* W1b = (const float*)d_in[5];
  const float* b1b = (const float*)d_in[6];
  const float* W2a = (const float*)d_in[7];
  const float* b2a = (const float*)d_in[8];
  const float* W2b = (const float*)d_in[9];
  const float* b2b = (const float*)d_in[10];
  const int*   e11s = (const int*)d_in[11];
  const int*   e11d = (const int*)d_in[12];
  const float* e11w = (const float*)d_in[13];
  const int*   e22s = (const int*)d_in[14];
  const int*   e22d = (const int*)d_in[15];
  const float* e22w = (const float*)d_in[16];
  const int*   e01s = (const int*)d_in[17];
  const int*   e01d = (const int*)d_in[18];
  const float* e01w = (const float*)d_in[19];
  const int*   e02s = (const int*)d_in[20];
  const int*   e02d = (const int*)d_in[21];
  const float* e02w = (const float*)d_in[22];

  const int N0 = 10000;
  const int N1 = in_sizes[0] / 256;
  const int N2 = in_sizes[1] / 256;
  const int E11 = in_sizes[11];
  const int E22 = in_sizes[14];
  const int E01 = in_sizes[17];
  const int E02 = in_sizes[20];

  float* out = (float*)d_out;

  // ---- workspace layout ----
  char* base = (char*)d_ws;
  auto alloc = [&](size_t bytes) -> void* {
    void* r = (void*)base;
    base += (bytes + 255) & ~(size_t)255;
    return r;
  };
  float* l1_1 = (float*)alloc((size_t)N1 * 128 * 4);
  float* l1_2 = (float*)alloc((size_t)N2 * 128 * 4);
  float* l2_1 = (float*)alloc((size_t)N1 * 128 * 4);
  float* l2_2 = (float*)alloc((size_t)N2 * 128 * 4);
  float* h11  = (float*)alloc((size_t)N1 * 128 * 4);
  float* h22  = (float*)alloc((size_t)N2 * 128 * 4);

  unsigned short* F1a = (unsigned short*)alloc(8 * 8 * 64 * 8 * 2);
  unsigned short* F1b = (unsigned short*)alloc(8 * 4 * 64 * 8 * 2);
  unsigned short* F2a = (unsigned short*)alloc(8 * 8 * 64 * 8 * 2);
  unsigned short* F2b = (unsigned short*)alloc(8 * 4 * 64 * 8 * 2);

  const int n11 = N1 + 1, n22 = N2 + 1, n01 = N0 + 1, n02 = N0 + 1;
  const int P1 = (n11 + 63) & ~63;
  const int P2 = (n22 + 63) & ~63;
  const int P0 = (n01 + 63) & ~63;
  int* cnt_all = (int*)alloc((size_t)(P1 + P2 + P0 + P0) * 4);
  int* cnt11 = cnt_all;
  int* cnt22 = cnt_all + P1;
  int* cnt01 = cnt_all + P1 + P2;
  int* cnt02 = cnt_all + P1 + P2 + P0;
  int* off11 = (int*)alloc((size_t)P1 * 4);
  int* off22 = (int*)alloc((size_t)P2 * 4);
  int* off01 = (int*)alloc((size_t)P0 * 4);
  int* off02 = (int*)alloc((size_t)P0 * 4);
  int* cur11 = (int*)alloc((size_t)P1 * 4);
  int* cur22 = (int*)alloc((size_t)P2 * 4);
  int* cur01 = (int*)alloc((size_t)P0 * 4);
  int* cur02 = (int*)alloc((size_t)P0 * 4);
  int2* pk11 = (int2*)alloc((size_t)E11 * 8);
  int2* pk22 = (int2*)alloc((size_t)E22 * 8);
  int2* pk01 = (int2*)alloc((size_t)E01 * 8);
  int2* pk02 = (int2*)alloc((size_t)E02 * 8);
  int* chunkSums = (int*)alloc(64 * 4);
  int* chunkOffs = (int*)alloc(64 * 4);

  const int nc11 = (n11 + CHUNK - 1) / CHUNK;
  const int nc22 = (n22 + CHUNK - 1) / CHUNK;
  const int nc01 = (n01 + CHUNK - 1) / CHUNK;
  const int nc02 = (n02 + CHUNK - 1) / CHUNK;
  const int TC = nc11 + nc22 + nc01 + nc02;
  const int Etot = E11 + E22 + E01 + E02;

  // ---- CSR build ----
  hipMemsetAsync(cnt_all, 0, (size_t)(P1 + P2 + P0 + P0) * 4, stream);
  hist_all_kernel<<<(Etot + 255) / 256, 256, 0, stream>>>(
      e11d, E11, cnt11, e22d, E22, cnt22, e01d, E01, cnt01, e02d, E02, cnt02);
  scan_local_kernel<<<TC, 256, 0, stream>>>(
      cnt11, off11, n11, cnt22, off22, n22, cnt01, off01, n01,
      cnt02, off02, n02, nc11, nc22, nc01, chunkSums);
  scan_sums_kernel<<<1, 64, 0, stream>>>(chunkSums, chunkOffs, nc11, nc22, nc01, TC);
  scan_add_kernel<<<TC, 256, 0, stream>>>(
      off11, cur11, n11, off22, cur22, n22, off01, cur01, n01,
      off02, cur02, n02, nc11, nc22, nc01, chunkOffs);
  scatter_all_kernel<<<(Etot + 255) / 256, 256, 0, stream>>>(
      e11s, e11d, e11w, E11, cur11, pk11, e22s, e22d, e22w, E22, cur22, pk22,
      e01s, e01d, e01w, E01, cur01, pk01, e02s, e02d, e02w, E02, cur02, pk02);

  // ---- weight conversion + layer 1 GEMMs (bf16 MFMA) ----
  conv_w_kernel<<<48, 256, 0, stream>>>(W1a, W1b, W2a, W2b, F1a, F1b, F2a, F2b);
  gemm_mfma_kernel<256><<<(N1 + 63) / 64, 256, 0, stream>>>(x1, F1a, b1a, l1_1, N1);
  gemm_mfma_kernel<256><<<(N2 + 63) / 64, 256, 0, stream>>>(x2, F2a, b2a, l1_2, N2);

  // ---- layer 2: pull-spmm then GEMM ----
  pull_spmm_kernel<<<(N1 + 3) / 4, 256, 0, stream>>>(off11, pk11, l1_1, h11, N1);
  pull_spmm_kernel<<<(N2 + 3) / 4, 256, 0, stream>>>(off22, pk22, l1_2, h22, N2);
  gemm_mfma_kernel<128><<<(N1 + 63) / 64, 256, 0, stream>>>(h11, F1b, b1b, l2_1, N1);
  gemm_mfma_kernel<128><<<(N2 + 63) / 64, 256, 0, stream>>>(h22, F2b, b2b, l2_2, N2);

  // ---- doc aggregation + l2norm + concat (fused) ----
  pull_doc2_kernel<<<(N0 + 3) / 4, 256, 0, stream>>>(off01, pk01, l2_1, l1_1, out, N0);
  pull_doc3_kernel<<<(N0 + 3) / 4, 256, 0, stream>>>(off02, pk02, l2_2, l1_2, wem, out, N0);
}